// Round 1
// baseline (587.629 us; speedup 1.0000x reference)
//
#include <hip/hip_runtime.h>

// Problem constants
constexpr int Bb = 4;     // batch
constexpr int Dd = 256;   // channels
constexpr int Nn = 2048;  // query positions
constexpr int Mm = 2048;  // source positions
constexpr int Hh = 4;     // heads
constexpr int D2 = 512;   // 2*D

#define FMAXV 3.402823466e38f

// ---------------------------------------------------------------------------
// Fold eval-mode BatchNorm into W1/b1:  s = gamma*rsqrt(var+eps)
// W1f = W1*s ;  b1f = (b1-rmean)*s + beta
// ---------------------------------------------------------------------------
__global__ void fold_bn_kernel(const float* __restrict__ W1, const float* __restrict__ b1,
                               const float* __restrict__ gamma, const float* __restrict__ beta,
                               const float* __restrict__ rmean, const float* __restrict__ rvar,
                               float* __restrict__ W1f, float* __restrict__ b1f) {
    const int o = blockIdx.x;  // 512 blocks
    const float s = gamma[o] * rsqrtf(rvar[o] + 1e-3f);
    for (int c = threadIdx.x; c < D2; c += blockDim.x)
        W1f[o * D2 + c] = W1[o * D2 + c] * s;
    if (threadIdx.x == 0) b1f[o] = (b1[o] - rmean[o]) * s + beta[o];
}

// ---------------------------------------------------------------------------
// Generic fp32 GEMM over positions:  out[b,o,n] = act(bias[o] + sum_c W[o,c]*X[b,c,n])
// X is the channel-concat of X1 (C1 channels) and X2 (K-C1 channels).
// Tile: 64 o x 64 n, K-tile 16. 256 threads, per-thread 4x4 outer product.
// ---------------------------------------------------------------------------
__global__ __launch_bounds__(256)
void gemm_kernel(const float* __restrict__ W, const float* __restrict__ bias,
                 const float* __restrict__ X1, const float* __restrict__ X2,
                 float* __restrict__ out, int K, int C1, int Orows, int relu) {
    __shared__ __align__(16) float Ws[16][68];  // [kk][oo]  (W transposed tile)
    __shared__ __align__(16) float Xs[16][68];  // [kk][nn]
    const int b = blockIdx.z;
    const int o0 = blockIdx.y * 64;
    const int n0 = blockIdx.x * 64;
    const int t = threadIdx.x;
    const int tx = t & 15, ty = t >> 4;
    float acc[4][4] = {};
    for (int k0 = 0; k0 < K; k0 += 16) {
        {   // stage W tile (transpose in LDS)
            const int oo = t >> 2, p = t & 3;
            float4 wv = *(const float4*)(W + (size_t)(o0 + oo) * K + k0 + p * 4);
            Ws[p * 4 + 0][oo] = wv.x;
            Ws[p * 4 + 1][oo] = wv.y;
            Ws[p * 4 + 2][oo] = wv.z;
            Ws[p * 4 + 3][oo] = wv.w;
        }
        {   // stage X tile (natural layout, coalesced)
            const int kk = t >> 4, part = t & 15;
            const int c = k0 + kk;
            const float* Xr = (c < C1) ? (X1 + ((size_t)b * C1 + c) * Nn)
                                       : (X2 + ((size_t)b * (K - C1) + (c - C1)) * Nn);
            *(float4*)(&Xs[kk][part * 4]) = *(const float4*)(Xr + n0 + part * 4);
        }
        __syncthreads();
        #pragma unroll
        for (int kk = 0; kk < 16; ++kk) {
            float4 wv = *(const float4*)(&Ws[kk][ty * 4]);
            float4 xv = *(const float4*)(&Xs[kk][tx * 4]);
            float w[4] = {wv.x, wv.y, wv.z, wv.w};
            float xx[4] = {xv.x, xv.y, xv.z, xv.w};
            #pragma unroll
            for (int i = 0; i < 4; ++i)
                #pragma unroll
                for (int j = 0; j < 4; ++j)
                    acc[i][j] = fmaf(w[i], xx[j], acc[i][j]);
        }
        __syncthreads();
    }
    #pragma unroll
    for (int i = 0; i < 4; ++i) {
        const int o = o0 + ty * 4 + i;
        const float bv = bias[o];
        float v0 = acc[i][0] + bv, v1 = acc[i][1] + bv;
        float v2 = acc[i][2] + bv, v3 = acc[i][3] + bv;
        if (relu) {
            v0 = fmaxf(v0, 0.f); v1 = fmaxf(v1, 0.f);
            v2 = fmaxf(v2, 0.f); v3 = fmaxf(v3, 0.f);
        }
        *(float4*)(out + ((size_t)b * Orows + o) * Nn + n0 + tx * 4) =
            make_float4(v0, v1, v2, v3);
    }
}

// ---------------------------------------------------------------------------
// Flash-style masked attention. One block per (b, h, 64 query rows).
// q,k,v in [B, 256, pos] layout; head h uses channels c = d*H + h (d in [0,64)).
// Online softmax with -FLT_MAX masking (matches reference semantics).
// Writes msg[b, c, n].
// ---------------------------------------------------------------------------
__global__ __launch_bounds__(256)
void attn_kernel(const float* __restrict__ q, const float* __restrict__ k,
                 const float* __restrict__ v, const float* __restrict__ mask,
                 float* __restrict__ msg) {
    __shared__ __align__(16) float Qs[64][68];  // [d][n]
    __shared__ __align__(16) float Ks[64][68];  // [d][m]
    __shared__ __align__(16) float Vs[64][68];  // [m][d]  (transposed on load)
    __shared__ __align__(16) float Ss[64][68];  // [m][n]  (S transposed)
    __shared__ float Pm[4][64];
    __shared__ float Psum[4][64];
    __shared__ float rowm[64], rowl[64], rowa[64];

    const int b = blockIdx.z, h = blockIdx.y, n0 = blockIdx.x * 64;
    const int t = threadIdx.x;
    const int tx = t & 15, ty = t >> 4;
    const int part = t & 15, dr = t >> 4;
    const int nr = t & 63, qd = t >> 6;

    // Load Q tile: Qs[d][n]
    #pragma unroll
    for (int r = 0; r < 4; ++r) {
        const int d = dr + r * 16;
        const int c = d * Hh + h;
        *(float4*)(&Qs[d][part * 4]) =
            *(const float4*)(q + ((size_t)b * Dd + c) * Nn + n0 + part * 4);
    }
    if (t < 64) { rowm[t] = -FMAXV; rowl[t] = 0.f; }

    float O[4][4] = {};  // n = tx*4+i, d = ty*4+j

    for (int m0 = 0; m0 < Mm; m0 += 64) {
        __syncthreads();  // protect Ks/Vs/Ss/rowa reuse from previous iteration
        // Stage K (natural) and V (transposed) tiles
        #pragma unroll
        for (int r = 0; r < 4; ++r) {
            const int d = dr + r * 16;
            const int c = d * Hh + h;
            *(float4*)(&Ks[d][part * 4]) =
                *(const float4*)(k + ((size_t)b * Dd + c) * Nn + m0 + part * 4);
            float4 vv = *(const float4*)(v + ((size_t)b * Dd + c) * Nn + m0 + part * 4);
            Vs[part * 4 + 0][d] = vv.x;
            Vs[part * 4 + 1][d] = vv.y;
            Vs[part * 4 + 2][d] = vv.z;
            Vs[part * 4 + 3][d] = vv.w;
        }
        __syncthreads();

        // S = Q K^T over d; thread computes n = tx*4+i, m = ty*4+j
        float s[4][4] = {};
        #pragma unroll 16
        for (int d = 0; d < 64; ++d) {
            float4 qv = *(const float4*)(&Qs[d][tx * 4]);
            float4 kv = *(const float4*)(&Ks[d][ty * 4]);
            float qa[4] = {qv.x, qv.y, qv.z, qv.w};
            float ka[4] = {kv.x, kv.y, kv.z, kv.w};
            #pragma unroll
            for (int i = 0; i < 4; ++i)
                #pragma unroll
                for (int j = 0; j < 4; ++j)
                    s[i][j] = fmaf(qa[i], ka[j], s[i][j]);
        }
        // scale + mask
        #pragma unroll
        for (int i = 0; i < 4; ++i) {
            float4 mv = *(const float4*)(mask +
                ((size_t)b * Nn + n0 + tx * 4 + i) * Mm + m0 + ty * 4);
            s[i][0] = mv.x > 0.f ? s[i][0] * 0.125f : -FMAXV;
            s[i][1] = mv.y > 0.f ? s[i][1] * 0.125f : -FMAXV;
            s[i][2] = mv.z > 0.f ? s[i][2] * 0.125f : -FMAXV;
            s[i][3] = mv.w > 0.f ? s[i][3] * 0.125f : -FMAXV;
        }
        // store S transposed: Ss[m][n]
        #pragma unroll
        for (int j = 0; j < 4; ++j)
            *(float4*)(&Ss[ty * 4 + j][tx * 4]) =
                make_float4(s[0][j], s[1][j], s[2][j], s[3][j]);
        __syncthreads();

        // softmax phase A: partial tile max per row (4 thread-groups over m)
        float tm = -FMAXV;
        #pragma unroll
        for (int mm = 0; mm < 16; ++mm) tm = fmaxf(tm, Ss[qd * 16 + mm][nr]);
        Pm[qd][nr] = tm;
        __syncthreads();
        // phase B: combine, update running max, compute alpha
        if (t < 64) {
            float tmax = fmaxf(fmaxf(Pm[0][t], Pm[1][t]), fmaxf(Pm[2][t], Pm[3][t]));
            float mold = rowm[t];
            float mnew = fmaxf(mold, tmax);
            rowa[t] = __expf(mold - mnew);
            rowm[t] = mnew;
        }
        __syncthreads();
        // phase C: exponentiate in place, partial row sums
        {
            const float mn = rowm[nr];
            float rsum = 0.f;
            #pragma unroll
            for (int mm = 0; mm < 16; ++mm) {
                float p = __expf(Ss[qd * 16 + mm][nr] - mn);
                Ss[qd * 16 + mm][nr] = p;
                rsum += p;
            }
            Psum[qd][nr] = rsum;
        }
        __syncthreads();
        // phase D: update running denominator
        if (t < 64)
            rowl[t] = rowl[t] * rowa[t] + Psum[0][t] + Psum[1][t] + Psum[2][t] + Psum[3][t];

        // rescale O and accumulate P @ V
        #pragma unroll
        for (int i = 0; i < 4; ++i) {
            const float a = rowa[tx * 4 + i];
            #pragma unroll
            for (int j = 0; j < 4; ++j) O[i][j] *= a;
        }
        #pragma unroll 16
        for (int m = 0; m < 64; ++m) {
            float4 pv = *(const float4*)(&Ss[m][tx * 4]);
            float4 vv = *(const float4*)(&Vs[m][ty * 4]);
            float pa[4] = {pv.x, pv.y, pv.z, pv.w};
            float va[4] = {vv.x, vv.y, vv.z, vv.w};
            #pragma unroll
            for (int i = 0; i < 4; ++i)
                #pragma unroll
                for (int j = 0; j < 4; ++j)
                    O[i][j] = fmaf(pa[i], va[j], O[i][j]);
        }
    }
    __syncthreads();
    float rl[4];
    #pragma unroll
    for (int i = 0; i < 4; ++i) rl[i] = 1.0f / rowl[tx * 4 + i];
    #pragma unroll
    for (int j = 0; j < 4; ++j) {
        const int c = (ty * 4 + j) * Hh + h;  // channel = d*H + h
        *(float4*)(msg + ((size_t)b * Dd + c) * Nn + n0 + tx * 4) =
            make_float4(O[0][j] * rl[0], O[1][j] * rl[1],
                        O[2][j] * rl[2], O[3][j] * rl[3]);
    }
}

// ---------------------------------------------------------------------------
extern "C" void kernel_launch(void* const* d_in, const int* in_sizes, int n_in,
                              void* d_out, int out_size, void* d_ws, size_t ws_size,
                              hipStream_t stream) {
    const float* x      = (const float*)d_in[0];
    const float* source = (const float*)d_in[1];
    const float* mask   = (const float*)d_in[2];
    const float* Wq = (const float*)d_in[3];
    const float* bq = (const float*)d_in[4];
    const float* Wk = (const float*)d_in[5];
    const float* bk = (const float*)d_in[6];
    const float* Wv = (const float*)d_in[7];
    const float* bv = (const float*)d_in[8];
    const float* Wm = (const float*)d_in[9];
    const float* bm = (const float*)d_in[10];
    const float* W1 = (const float*)d_in[11];
    const float* b1 = (const float*)d_in[12];
    const float* gamma = (const float*)d_in[13];
    const float* beta  = (const float*)d_in[14];
    const float* rmean = (const float*)d_in[15];
    const float* rvar  = (const float*)d_in[16];
    const float* W2 = (const float*)d_in[17];
    const float* b2 = (const float*)d_in[18];
    float* outp = (float*)d_out;

    float* ws = (float*)d_ws;
    const size_t SZ = (size_t)Bb * Dd * Nn;  // 2,097,152 floats
    float* qb      = ws;             // [B,256,N]
    float* kb      = ws + SZ;        // [B,256,M]
    float* vb      = ws + 2 * SZ;    // [B,256,M]
    float* msgb    = ws + 3 * SZ;    // attention output [B,256,N]
    float* msgproj = ws;             // message = Wm@msg (reuses qb)
    float* hb      = ws + SZ;        // MLP hidden [B,512,N] (reuses kb+vb)
    float* W1f     = ws + 4 * SZ;    // 512*512 folded weights
    float* b1f     = W1f + D2 * D2;  // 512 folded bias

    fold_bn_kernel<<<D2, 256, 0, stream>>>(W1, b1, gamma, beta, rmean, rvar, W1f, b1f);

    dim3 gProj(Nn / 64, Dd / 64, Bb);   // (32,4,4)
    gemm_kernel<<<gProj, 256, 0, stream>>>(Wq, bq, x,      nullptr, qb, Dd, Dd, Dd, 0);
    gemm_kernel<<<gProj, 256, 0, stream>>>(Wk, bk, source, nullptr, kb, Dd, Dd, Dd, 0);
    gemm_kernel<<<gProj, 256, 0, stream>>>(Wv, bv, source, nullptr, vb, Dd, Dd, Dd, 0);

    dim3 gAttn(Nn / 64, Hh, Bb);        // (32,4,4)
    attn_kernel<<<gAttn, 256, 0, stream>>>(qb, kb, vb, mask, msgb);

    gemm_kernel<<<gProj, 256, 0, stream>>>(Wm, bm, msgb, nullptr, msgproj, Dd, Dd, Dd, 0);

    dim3 gW1(Nn / 64, D2 / 64, Bb);     // (32,8,4)
    gemm_kernel<<<gW1, 256, 0, stream>>>(W1f, b1f, x, msgproj, hb, D2, Dd, D2, 1);

    gemm_kernel<<<gProj, 256, 0, stream>>>(W2, b2, hb, nullptr, outp, D2, D2, Dd, 0);
}

// Round 2
// 441.607 us; speedup vs baseline: 1.3307x; 1.3307x over previous
//
#include <hip/hip_runtime.h>

// Problem constants
constexpr int Bb = 4;     // batch
constexpr int Dd = 256;   // channels
constexpr int Nn = 2048;  // query positions
constexpr int Mm = 2048;  // source positions
constexpr int Hh = 4;     // heads
constexpr int D2 = 512;   // 2*D

#define FMAXV 3.402823466e38f

typedef _Float16 half8 __attribute__((ext_vector_type(8)));
typedef float f32x4 __attribute__((ext_vector_type(4)));

// ---------------------------------------------------------------------------
// Fold eval-mode BatchNorm into W1/b1
// ---------------------------------------------------------------------------
__global__ void fold_bn_kernel(const float* __restrict__ W1, const float* __restrict__ b1,
                               const float* __restrict__ gamma, const float* __restrict__ beta,
                               const float* __restrict__ rmean, const float* __restrict__ rvar,
                               float* __restrict__ W1f, float* __restrict__ b1f) {
    const int o = blockIdx.x;
    const float s = gamma[o] * rsqrtf(rvar[o] + 1e-3f);
    for (int c = threadIdx.x; c < D2; c += blockDim.x)
        W1f[o * D2 + c] = W1[o * D2 + c] * s;
    if (threadIdx.x == 0) b1f[o] = (b1[o] - rmean[o]) * s + beta[o];
}

// ---------------------------------------------------------------------------
// Generic fp32 GEMM (unchanged from round 1): out[b,o,n] = act(bias + W@X)
// ---------------------------------------------------------------------------
__global__ __launch_bounds__(256)
void gemm_kernel(const float* __restrict__ W, const float* __restrict__ bias,
                 const float* __restrict__ X1, const float* __restrict__ X2,
                 float* __restrict__ out, int K, int C1, int Orows, int relu) {
    __shared__ __align__(16) float Ws[16][68];
    __shared__ __align__(16) float Xs[16][68];
    const int b = blockIdx.z;
    const int o0 = blockIdx.y * 64;
    const int n0 = blockIdx.x * 64;
    const int t = threadIdx.x;
    const int tx = t & 15, ty = t >> 4;
    float acc[4][4] = {};
    for (int k0 = 0; k0 < K; k0 += 16) {
        {
            const int oo = t >> 2, p = t & 3;
            float4 wv = *(const float4*)(W + (size_t)(o0 + oo) * K + k0 + p * 4);
            Ws[p * 4 + 0][oo] = wv.x;
            Ws[p * 4 + 1][oo] = wv.y;
            Ws[p * 4 + 2][oo] = wv.z;
            Ws[p * 4 + 3][oo] = wv.w;
        }
        {
            const int kk = t >> 4, part = t & 15;
            const int c = k0 + kk;
            const float* Xr = (c < C1) ? (X1 + ((size_t)b * C1 + c) * Nn)
                                       : (X2 + ((size_t)b * (K - C1) + (c - C1)) * Nn);
            *(float4*)(&Xs[kk][part * 4]) = *(const float4*)(Xr + n0 + part * 4);
        }
        __syncthreads();
        #pragma unroll
        for (int kk = 0; kk < 16; ++kk) {
            float4 wv = *(const float4*)(&Ws[kk][ty * 4]);
            float4 xv = *(const float4*)(&Xs[kk][tx * 4]);
            float w[4] = {wv.x, wv.y, wv.z, wv.w};
            float xx[4] = {xv.x, xv.y, xv.z, xv.w};
            #pragma unroll
            for (int i = 0; i < 4; ++i)
                #pragma unroll
                for (int j = 0; j < 4; ++j)
                    acc[i][j] = fmaf(w[i], xx[j], acc[i][j]);
        }
        __syncthreads();
    }
    #pragma unroll
    for (int i = 0; i < 4; ++i) {
        const int o = o0 + ty * 4 + i;
        const float bv = bias[o];
        float v0 = acc[i][0] + bv, v1 = acc[i][1] + bv;
        float v2 = acc[i][2] + bv, v3 = acc[i][3] + bv;
        if (relu) {
            v0 = fmaxf(v0, 0.f); v1 = fmaxf(v1, 0.f);
            v2 = fmaxf(v2, 0.f); v3 = fmaxf(v3, 0.f);
        }
        *(float4*)(out + ((size_t)b * Orows + o) * Nn + n0 + tx * 4) =
            make_float4(v0, v1, v2, v3);
    }
}

// ---------------------------------------------------------------------------
// Prepack: fp32 q/k [B,256,pos] -> fp16 Qt/Kt [b][h][pos][64] (d contiguous),
//          fp32 v  -> fp16 Vt [b][h][64][2048] (m contiguous).
// Channel c = d*H + h.
// ---------------------------------------------------------------------------
__global__ __launch_bounds__(256)
void prepack_kernel(const float* __restrict__ qb, const float* __restrict__ kb,
                    const float* __restrict__ vb,
                    _Float16* __restrict__ Qt, _Float16* __restrict__ Kt,
                    _Float16* __restrict__ Vt) {
    const int z = blockIdx.z;
    const int b = z / 3, sel = z % 3;
    const int h = blockIdx.y;
    const int p0 = blockIdx.x * 64;
    const int t = threadIdx.x;
    const size_t bh = (size_t)b * Hh + h;

    if (sel < 2) {
        // transpose path: [d][pos] -> [pos][d]
        __shared__ _Float16 Ts[64][72];
        const float* src = (sel == 0) ? qb : kb;
        _Float16* dst = (sel == 0) ? Qt : Kt;
        const int d = t >> 2, np = (t & 3) * 16;
        const float* sp = src + ((size_t)b * Dd + d * Hh + h) * Nn + p0 + np;
        #pragma unroll
        for (int i = 0; i < 4; ++i) {
            float4 v = *(const float4*)(sp + i * 4);
            Ts[np + i * 4 + 0][d] = (_Float16)v.x;
            Ts[np + i * 4 + 1][d] = (_Float16)v.y;
            Ts[np + i * 4 + 2][d] = (_Float16)v.z;
            Ts[np + i * 4 + 3][d] = (_Float16)v.w;
        }
        __syncthreads();
        const int n = t >> 2, dp = (t & 3) * 16;
        half8 a = *(const half8*)&Ts[n][dp];
        half8 c = *(const half8*)&Ts[n][dp + 8];
        _Float16* dp_out = dst + ((bh * Nn) + p0 + n) * 64 + dp;
        *(half8*)(dp_out) = a;
        *(half8*)(dp_out + 8) = c;
    } else {
        // V: straight convert, keep [d][m] layout
        const int d = t >> 2, mp = (t & 3) * 16;
        const float* sp = vb + ((size_t)b * Dd + d * Hh + h) * Mm + p0 + mp;
        _Float16 tmp[16];
        #pragma unroll
        for (int i = 0; i < 4; ++i) {
            float4 v = *(const float4*)(sp + i * 4);
            tmp[i * 4 + 0] = (_Float16)v.x;
            tmp[i * 4 + 1] = (_Float16)v.y;
            tmp[i * 4 + 2] = (_Float16)v.z;
            tmp[i * 4 + 3] = (_Float16)v.w;
        }
        _Float16* op = Vt + (bh * 64 + d) * (size_t)Mm + p0 + mp;
        *(half8*)(op) = *(half8*)(tmp);
        *(half8*)(op + 8) = *(half8*)(tmp + 8);
    }
}

// ---------------------------------------------------------------------------
// MFMA flash attention. Grid (N/64, H, B), 256 threads = 4 waves.
// Wave w owns query rows [n0+16w, n0+16w+16) — private online-softmax state,
// no __syncthreads in the K-loop. Q/K/V fragments load directly from global
// (pre-packed layouts make fragment loads coalesced). P round-trips through
// wave-private LDS for the C-layout -> A-layout transform.
// ---------------------------------------------------------------------------
__global__ __launch_bounds__(256)
void attn_mfma_kernel(const _Float16* __restrict__ Qt, const _Float16* __restrict__ Kt,
                      const _Float16* __restrict__ Vt, const float* __restrict__ mask,
                      float* __restrict__ msg) {
    __shared__ _Float16 Ps[4][16][72];   // per-wave P tiles (16n x 64m)
    __shared__ float Os[4][16][68];      // per-wave O transpose staging

    const int b = blockIdx.z, h = blockIdx.y, n0 = blockIdx.x * 64;
    const int t = threadIdx.x;
    const int w = t >> 6, lane = t & 63, quad = lane >> 4, l16 = lane & 15;
    const size_t bh = (size_t)b * Hh + h;

    // Q A-fragments for this wave's 16 rows (held all kernel)
    const _Float16* qp = Qt + ((bh * Nn) + n0 + w * 16 + l16) * 64 + quad * 8;
    const half8 qa0 = *(const half8*)(qp);
    const half8 qa1 = *(const half8*)(qp + 32);

    const _Float16* Kbase = Kt + (bh * Mm) * 64;
    const _Float16* Vbase = Vt + (bh * 64 + l16) * (size_t)Mm;
    const float* mrow = mask + ((size_t)b * Nn + n0 + w * 16 + quad * 4) * Mm + l16;

    float mo[4] = {-FMAXV, -FMAXV, -FMAXV, -FMAXV};
    float lo[4] = {0.f, 0.f, 0.f, 0.f};
    f32x4 O[4] = {};  // O[dt][reg]: rows n=quad*4+reg, cols d=dt*16+l16

    #pragma unroll 1
    for (int m0 = 0; m0 < Mm; m0 += 64) {
        // ---- S = Q K^T (16n x 64m in 4 C-frags) ----
        f32x4 S[4];
        #pragma unroll
        for (int mt = 0; mt < 4; ++mt) {
            const _Float16* kp = Kbase + (size_t)(m0 + mt * 16 + l16) * 64 + quad * 8;
            half8 k0 = *(const half8*)(kp);
            half8 k1 = *(const half8*)(kp + 32);
            f32x4 z = {0.f, 0.f, 0.f, 0.f};
            z = __builtin_amdgcn_mfma_f32_16x16x32_f16(qa0, k0, z, 0, 0, 0);
            z = __builtin_amdgcn_mfma_f32_16x16x32_f16(qa1, k1, z, 0, 0, 0);
            S[mt] = z;
        }
        // ---- mask + scale ----
        float mk[4][4];
        #pragma unroll
        for (int mt = 0; mt < 4; ++mt)
            #pragma unroll
            for (int reg = 0; reg < 4; ++reg)
                mk[mt][reg] = mrow[(size_t)reg * Mm + m0 + mt * 16];
        #pragma unroll
        for (int mt = 0; mt < 4; ++mt)
            #pragma unroll
            for (int reg = 0; reg < 4; ++reg)
                S[mt][reg] = (mk[mt][reg] > 0.f) ? S[mt][reg] * 0.125f : -FMAXV;

        // ---- online softmax (per-wave private rows) ----
        float mn[4], al[4], p[4][4], rs[4];
        #pragma unroll
        for (int reg = 0; reg < 4; ++reg) {
            float mloc = fmaxf(fmaxf(S[0][reg], S[1][reg]), fmaxf(S[2][reg], S[3][reg]));
            #pragma unroll
            for (int off = 1; off < 16; off <<= 1)
                mloc = fmaxf(mloc, __shfl_xor(mloc, off));
            mn[reg] = fmaxf(mo[reg], mloc);
            al[reg] = __expf(mo[reg] - mn[reg]);
            mo[reg] = mn[reg];
        }
        #pragma unroll
        for (int reg = 0; reg < 4; ++reg) {
            float s0 = __expf(S[0][reg] - mn[reg]);
            float s1 = __expf(S[1][reg] - mn[reg]);
            float s2 = __expf(S[2][reg] - mn[reg]);
            float s3 = __expf(S[3][reg] - mn[reg]);
            p[0][reg] = s0; p[1][reg] = s1; p[2][reg] = s2; p[3][reg] = s3;
            float rsum = (s0 + s1) + (s2 + s3);
            #pragma unroll
            for (int off = 1; off < 16; off <<= 1)
                rsum += __shfl_xor(rsum, off);
            rs[reg] = rsum;
            lo[reg] = lo[reg] * al[reg] + rs[reg];
        }
        // ---- P -> LDS (C-layout -> A-layout) ----
        #pragma unroll
        for (int mt = 0; mt < 4; ++mt)
            #pragma unroll
            for (int reg = 0; reg < 4; ++reg)
                Ps[w][quad * 4 + reg][mt * 16 + l16] = (_Float16)p[mt][reg];
        __asm__ volatile("s_waitcnt lgkmcnt(0)" ::: "memory");
        half8 pa0 = *(const half8*)&Ps[w][l16][quad * 8];
        half8 pa1 = *(const half8*)&Ps[w][l16][32 + quad * 8];

        // ---- rescale O, accumulate P @ V ----
        #pragma unroll
        for (int dt = 0; dt < 4; ++dt)
            #pragma unroll
            for (int reg = 0; reg < 4; ++reg)
                O[dt][reg] *= al[reg];
        #pragma unroll
        for (int dt = 0; dt < 4; ++dt) {
            const _Float16* vp = Vbase + (size_t)(dt * 16) * Mm + m0 + quad * 8;
            half8 v0 = *(const half8*)(vp);
            half8 v1 = *(const half8*)(vp + 32);
            O[dt] = __builtin_amdgcn_mfma_f32_16x16x32_f16(pa0, v0, O[dt], 0, 0, 0);
            O[dt] = __builtin_amdgcn_mfma_f32_16x16x32_f16(pa1, v1, O[dt], 0, 0, 0);
        }
    }

    // ---- normalize + transpose through LDS for coalesced stores ----
    float rl[4];
    #pragma unroll
    for (int reg = 0; reg < 4; ++reg) rl[reg] = 1.0f / lo[reg];
    #pragma unroll
    for (int dt = 0; dt < 4; ++dt)
        #pragma unroll
        for (int reg = 0; reg < 4; ++reg)
            Os[w][quad * 4 + reg][dt * 16 + l16] = O[dt][reg] * rl[reg];
    __syncthreads();
    // lane d = lane; 16 n-contiguous values -> one 64B line per lane
    float vv[16];
    #pragma unroll
    for (int j = 0; j < 16; ++j) vv[j] = Os[w][j][lane];
    float* op = msg + ((size_t)b * Dd + lane * Hh + h) * Nn + n0 + w * 16;
    #pragma unroll
    for (int i = 0; i < 4; ++i)
        *(float4*)(op + i * 4) = make_float4(vv[i * 4], vv[i * 4 + 1], vv[i * 4 + 2], vv[i * 4 + 3]);
}

// ---------------------------------------------------------------------------
extern "C" void kernel_launch(void* const* d_in, const int* in_sizes, int n_in,
                              void* d_out, int out_size, void* d_ws, size_t ws_size,
                              hipStream_t stream) {
    const float* x      = (const float*)d_in[0];
    const float* source = (const float*)d_in[1];
    const float* mask   = (const float*)d_in[2];
    const float* Wq = (const float*)d_in[3];
    const float* bq = (const float*)d_in[4];
    const float* Wk = (const float*)d_in[5];
    const float* bk = (const float*)d_in[6];
    const float* Wv = (const float*)d_in[7];
    const float* bv = (const float*)d_in[8];
    const float* Wm = (const float*)d_in[9];
    const float* bm = (const float*)d_in[10];
    const float* W1 = (const float*)d_in[11];
    const float* b1 = (const float*)d_in[12];
    const float* gamma = (const float*)d_in[13];
    const float* beta  = (const float*)d_in[14];
    const float* rmean = (const float*)d_in[15];
    const float* rvar  = (const float*)d_in[16];
    const float* W2 = (const float*)d_in[17];
    const float* b2 = (const float*)d_in[18];
    float* outp = (float*)d_out;

    float* ws = (float*)d_ws;
    const size_t SZ = (size_t)Bb * Dd * Nn;  // 2,097,152 floats
    float* qb      = ws;
    float* kb      = ws + SZ;
    float* vb      = ws + 2 * SZ;
    float* msgb    = ws + 3 * SZ;
    float* msgproj = ws;             // reuses qb after attention
    float* hb      = ws + SZ;        // reuses kb+vb after prepack
    float* W1f     = ws + 4 * SZ;
    float* b1f     = W1f + D2 * D2;
    _Float16* Qt = (_Float16*)(ws + 4 * SZ + D2 * D2 + D2);
    _Float16* Kt = Qt + (size_t)Bb * Hh * Nn * 64;
    _Float16* Vt = Kt + (size_t)Bb * Hh * Mm * 64;

    fold_bn_kernel<<<D2, 256, 0, stream>>>(W1, b1, gamma, beta, rmean, rvar, W1f, b1f);

    dim3 gProj(Nn / 64, Dd / 64, Bb);
    gemm_kernel<<<gProj, 256, 0, stream>>>(Wq, bq, x,      nullptr, qb, Dd, Dd, Dd, 0);
    gemm_kernel<<<gProj, 256, 0, stream>>>(Wk, bk, source, nullptr, kb, Dd, Dd, Dd, 0);
    gemm_kernel<<<gProj, 256, 0, stream>>>(Wv, bv, source, nullptr, vb, Dd, Dd, Dd, 0);

    dim3 gPack(Nn / 64, Hh, Bb * 3);
    prepack_kernel<<<gPack, 256, 0, stream>>>(qb, kb, vb, Qt, Kt, Vt);

    dim3 gAttn(Nn / 64, Hh, Bb);
    attn_mfma_kernel<<<gAttn, 256, 0, stream>>>(Qt, Kt, Vt, mask, msgb);

    gemm_kernel<<<gProj, 256, 0, stream>>>(Wm, bm, msgb, nullptr, msgproj, Dd, Dd, Dd, 0);

    dim3 gW1(Nn / 64, D2 / 64, Bb);
    gemm_kernel<<<gW1, 256, 0, stream>>>(W1f, b1f, x, msgproj, hb, D2, Dd, D2, 1);

    gemm_kernel<<<gProj, 256, 0, stream>>>(W2, b2, hb, nullptr, outp, D2, D2, Dd, 0);
}

// Round 7
// 440.121 us; speedup vs baseline: 1.3352x; 1.0034x over previous
//
#include <hip/hip_runtime.h>

// Problem constants
constexpr int Bb = 4;     // batch
constexpr int Dd = 256;   // channels
constexpr int Nn = 2048;  // query positions
constexpr int Mm = 2048;  // source positions
constexpr int Hh = 4;     // heads
constexpr int D2 = 512;   // 2*D

#define FMAXV 3.402823466e38f

typedef _Float16 half8 __attribute__((ext_vector_type(8)));
typedef float f32x4 __attribute__((ext_vector_type(4)));

// ---------------------------------------------------------------------------
// Fold eval-mode BatchNorm into W1/b1
// ---------------------------------------------------------------------------
__global__ void fold_bn_kernel(const float* __restrict__ W1, const float* __restrict__ b1,
                               const float* __restrict__ gamma, const float* __restrict__ beta,
                               const float* __restrict__ rmean, const float* __restrict__ rvar,
                               float* __restrict__ W1f, float* __restrict__ b1f) {
    const int o = blockIdx.x;
    const float s = gamma[o] * rsqrtf(rvar[o] + 1e-3f);
    for (int c = threadIdx.x; c < D2; c += blockDim.x)
        W1f[o * D2 + c] = W1[o * D2 + c] * s;
    if (threadIdx.x == 0) b1f[o] = (b1[o] - rmean[o]) * s + beta[o];
}

// ---------------------------------------------------------------------------
// Generic fp32 GEMM: out[b,o,n] = act(bias + W@X), X = concat(X1,X2) channels
// ---------------------------------------------------------------------------
__global__ __launch_bounds__(256)
void gemm_kernel(const float* __restrict__ W, const float* __restrict__ bias,
                 const float* __restrict__ X1, const float* __restrict__ X2,
                 float* __restrict__ out, int K, int C1, int Orows, int relu) {
    __shared__ __align__(16) float Ws[16][68];
    __shared__ __align__(16) float Xs[16][68];
    const int b = blockIdx.z;
    const int o0 = blockIdx.y * 64;
    const int n0 = blockIdx.x * 64;
    const int t = threadIdx.x;
    const int tx = t & 15, ty = t >> 4;
    float acc[4][4] = {};
    for (int k0 = 0; k0 < K; k0 += 16) {
        {
            const int oo = t >> 2, p = t & 3;
            float4 wv = *(const float4*)(W + (size_t)(o0 + oo) * K + k0 + p * 4);
            Ws[p * 4 + 0][oo] = wv.x;
            Ws[p * 4 + 1][oo] = wv.y;
            Ws[p * 4 + 2][oo] = wv.z;
            Ws[p * 4 + 3][oo] = wv.w;
        }
        {
            const int kk = t >> 4, part = t & 15;
            const int c = k0 + kk;
            const float* Xr = (c < C1) ? (X1 + ((size_t)b * C1 + c) * Nn)
                                       : (X2 + ((size_t)b * (K - C1) + (c - C1)) * Nn);
            *(float4*)(&Xs[kk][part * 4]) = *(const float4*)(Xr + n0 + part * 4);
        }
        __syncthreads();
        #pragma unroll
        for (int kk = 0; kk < 16; ++kk) {
            float4 wv = *(const float4*)(&Ws[kk][ty * 4]);
            float4 xv = *(const float4*)(&Xs[kk][tx * 4]);
            float w[4] = {wv.x, wv.y, wv.z, wv.w};
            float xx[4] = {xv.x, xv.y, xv.z, xv.w};
            #pragma unroll
            for (int i = 0; i < 4; ++i)
                #pragma unroll
                for (int j = 0; j < 4; ++j)
                    acc[i][j] = fmaf(w[i], xx[j], acc[i][j]);
        }
        __syncthreads();
    }
    #pragma unroll
    for (int i = 0; i < 4; ++i) {
        const int o = o0 + ty * 4 + i;
        const float bv = bias[o];
        float v0 = acc[i][0] + bv, v1 = acc[i][1] + bv;
        float v2 = acc[i][2] + bv, v3 = acc[i][3] + bv;
        if (relu) {
            v0 = fmaxf(v0, 0.f); v1 = fmaxf(v1, 0.f);
            v2 = fmaxf(v2, 0.f); v3 = fmaxf(v3, 0.f);
        }
        *(float4*)(out + ((size_t)b * Orows + o) * Nn + n0 + tx * 4) =
            make_float4(v0, v1, v2, v3);
    }
}

// ---------------------------------------------------------------------------
// Prepack q/k -> fp16 [b][h][pos][64] (d contiguous), v -> fp16 [b][h][64][m]
// ---------------------------------------------------------------------------
__global__ __launch_bounds__(256)
void prepack_kernel(const float* __restrict__ qb, const float* __restrict__ kb,
                    const float* __restrict__ vb,
                    _Float16* __restrict__ Qt, _Float16* __restrict__ Kt,
                    _Float16* __restrict__ Vt) {
    const int z = blockIdx.z;
    const int b = z / 3, sel = z % 3;
    const int h = blockIdx.y;
    const int p0 = blockIdx.x * 64;
    const int t = threadIdx.x;
    const size_t bh = (size_t)b * Hh + h;

    if (sel < 2) {
        __shared__ _Float16 Ts[64][72];
        const float* src = (sel == 0) ? qb : kb;
        _Float16* dst = (sel == 0) ? Qt : Kt;
        const int d = t >> 2, np = (t & 3) * 16;
        const float* sp = src + ((size_t)b * Dd + d * Hh + h) * Nn + p0 + np;
        #pragma unroll
        for (int i = 0; i < 4; ++i) {
            float4 v = *(const float4*)(sp + i * 4);
            Ts[np + i * 4 + 0][d] = (_Float16)v.x;
            Ts[np + i * 4 + 1][d] = (_Float16)v.y;
            Ts[np + i * 4 + 2][d] = (_Float16)v.z;
            Ts[np + i * 4 + 3][d] = (_Float16)v.w;
        }
        __syncthreads();
        const int n = t >> 2, dp = (t & 3) * 16;
        half8 a = *(const half8*)&Ts[n][dp];
        half8 c = *(const half8*)&Ts[n][dp + 8];
        _Float16* dp_out = dst + ((bh * Nn) + p0 + n) * 64 + dp;
        *(half8*)(dp_out) = a;
        *(half8*)(dp_out + 8) = c;
    } else {
        const int d = t >> 2, mp = (t & 3) * 16;
        const float* sp = vb + ((size_t)b * Dd + d * Hh + h) * Mm + p0 + mp;
        _Float16 tmp[16];
        #pragma unroll
        for (int i = 0; i < 4; ++i) {
            float4 v = *(const float4*)(sp + i * 4);
            tmp[i * 4 + 0] = (_Float16)v.x;
            tmp[i * 4 + 1] = (_Float16)v.y;
            tmp[i * 4 + 2] = (_Float16)v.z;
            tmp[i * 4 + 3] = (_Float16)v.w;
        }
        _Float16* op = Vt + (bh * 64 + d) * (size_t)Mm + p0 + mp;
        *(half8*)(op) = *(half8*)(tmp);
        *(half8*)(op + 8) = *(half8*)(tmp + 8);
    }
}

// ---------------------------------------------------------------------------
// MFMA attention with per-wave ONLINE MAX restored inside the m-split.
// BISECTION vs round 6 (single semantic delta): softmax max subtraction is
// back. Wave w handles m in [w*512, w*512+512) with running (max, rescale);
// epilogue combines wave partials max-aware:
//   m* = max_w m_w;  O = sum_w exp(m_w-m*) O_w;  L = sum_w exp(m_w-m*) l_w.
// Grid (N/16, H, B) = 2048 blocks, 256 thr.
// ---------------------------------------------------------------------------
__global__ __launch_bounds__(256)
void attn_mfma_kernel(const _Float16* __restrict__ Qt, const _Float16* __restrict__ Kt,
                      const _Float16* __restrict__ Vt, const float* __restrict__ mask,
                      float* __restrict__ msg) {
    __shared__ __align__(16) _Float16 Ps[4][16][72];  // per-wave P tiles
    __shared__ __align__(16) float Osw[4][16][68];    // wave partial O
    __shared__ float Lw[4][16];                       // wave partial row sums
    __shared__ float Mw[4][16];                       // wave row maxima

    const int b = blockIdx.z, h = blockIdx.y, n0 = blockIdx.x * 16;
    const int t = threadIdx.x;
    const int w = t >> 6, lane = t & 63, quad = lane >> 4, l16 = lane & 15;
    const size_t bh = (size_t)b * Hh + h;

    // Q A-fragments for the block's 16 rows (same for all waves)
    const _Float16* qp = Qt + ((bh * Nn) + n0 + l16) * 64 + quad * 8;
    const half8 qa0 = *(const half8*)(qp);
    const half8 qa1 = *(const half8*)(qp + 32);

    const _Float16* Kbase = Kt + (bh * Mm) * 64;
    const _Float16* Vbase = Vt + (bh * 64 + l16) * (size_t)Mm;
    // mask element (n = n0+quad*4+reg, m = m0+mt*16+l16)
    const float* mrow = mask + ((size_t)b * Nn + n0 + quad * 4) * Mm + l16;

    float mo[4] = {-FMAXV, -FMAXV, -FMAXV, -FMAXV};
    float lo[4] = {0.f, 0.f, 0.f, 0.f};   // lane-local partial row sums
    f32x4 O[4] = {};  // O[dt][reg]: row n=quad*4+reg, col d=dt*16+l16

    const int mbeg = w * (Mm / 4);
    #pragma unroll 1
    for (int it = 0; it < (Mm / 4) / 64; ++it) {
        const int m0 = mbeg + it * 64;
        // ---- S = Q K^T ----
        f32x4 S[4];
        #pragma unroll
        for (int mt = 0; mt < 4; ++mt) {
            const _Float16* kp = Kbase + (size_t)(m0 + mt * 16 + l16) * 64 + quad * 8;
            half8 k0 = *(const half8*)(kp);
            half8 k1 = *(const half8*)(kp + 32);
            f32x4 z = {0.f, 0.f, 0.f, 0.f};
            z = __builtin_amdgcn_mfma_f32_16x16x32_f16(qa0, k0, z, 0, 0, 0);
            z = __builtin_amdgcn_mfma_f32_16x16x32_f16(qa1, k1, z, 0, 0, 0);
            S[mt] = z;
        }
        // ---- mask + scale ----
        float mk[4][4];
        #pragma unroll
        for (int mt = 0; mt < 4; ++mt)
            #pragma unroll
            for (int reg = 0; reg < 4; ++reg)
                mk[mt][reg] = mrow[(size_t)reg * Mm + m0 + mt * 16];
        #pragma unroll
        for (int mt = 0; mt < 4; ++mt)
            #pragma unroll
            for (int reg = 0; reg < 4; ++reg)
                S[mt][reg] = (mk[mt][reg] > 0.f) ? S[mt][reg] * 0.125f : -FMAXV;
        // ---- online max (per row, over this wave's tile) ----
        float mn[4], al[4];
        #pragma unroll
        for (int reg = 0; reg < 4; ++reg) {
            float mloc = fmaxf(fmaxf(S[0][reg], S[1][reg]), fmaxf(S[2][reg], S[3][reg]));
            #pragma unroll
            for (int off = 1; off < 16; off <<= 1)
                mloc = fmaxf(mloc, __shfl_xor(mloc, off));
            mn[reg] = fmaxf(mo[reg], mloc);
            al[reg] = __expf(mo[reg] - mn[reg]);
            mo[reg] = mn[reg];
        }
        // ---- p = exp(s - mn); lane-local row-sum with rescale ----
        float p[4][4];
        #pragma unroll
        for (int mt = 0; mt < 4; ++mt)
            #pragma unroll
            for (int reg = 0; reg < 4; ++reg)
                p[mt][reg] = __expf(S[mt][reg] - mn[reg]);
        #pragma unroll
        for (int reg = 0; reg < 4; ++reg)
            lo[reg] = lo[reg] * al[reg] + (p[0][reg] + p[1][reg]) + (p[2][reg] + p[3][reg]);
        // ---- P -> LDS (C-layout -> A-layout) ----
        #pragma unroll
        for (int mt = 0; mt < 4; ++mt)
            #pragma unroll
            for (int reg = 0; reg < 4; ++reg)
                Ps[w][quad * 4 + reg][mt * 16 + l16] = (_Float16)p[mt][reg];
        __asm__ volatile("s_waitcnt lgkmcnt(0)" ::: "memory");
        half8 pa0 = *(const half8*)&Ps[w][l16][quad * 8];
        half8 pa1 = *(const half8*)&Ps[w][l16][32 + quad * 8];
        // ---- rescale O, accumulate P @ V ----
        #pragma unroll
        for (int dt = 0; dt < 4; ++dt)
            #pragma unroll
            for (int reg = 0; reg < 4; ++reg)
                O[dt][reg] *= al[reg];
        #pragma unroll
        for (int dt = 0; dt < 4; ++dt) {
            const _Float16* vp = Vbase + (size_t)(dt * 16) * Mm + m0 + quad * 8;
            half8 v0 = *(const half8*)(vp);
            half8 v1 = *(const half8*)(vp + 32);
            O[dt] = __builtin_amdgcn_mfma_f32_16x16x32_f16(pa0, v0, O[dt], 0, 0, 0);
            O[dt] = __builtin_amdgcn_mfma_f32_16x16x32_f16(pa1, v1, O[dt], 0, 0, 0);
        }
    }

    // ---- reduce lane-local row sums over the 16 lanes of each quad ----
    #pragma unroll
    for (int reg = 0; reg < 4; ++reg) {
        #pragma unroll
        for (int off = 1; off < 16; off <<= 1)
            lo[reg] += __shfl_xor(lo[reg], off);
    }

    // ---- wave partials -> LDS ----
    #pragma unroll
    for (int dt = 0; dt < 4; ++dt)
        #pragma unroll
        for (int reg = 0; reg < 4; ++reg)
            Osw[w][quad * 4 + reg][dt * 16 + l16] = O[dt][reg];
    if (l16 == 0) {
        #pragma unroll
        for (int reg = 0; reg < 4; ++reg) {
            Lw[w][quad * 4 + reg] = lo[reg];
            Mw[w][quad * 4 + reg] = mo[reg];
        }
    }
    __syncthreads();

    // ---- max-aware combine of 4 wave partials, store msg[b][d*H+h][n] ----
    const int d = t >> 2, g = t & 3;
    float vals[4];
    #pragma unroll
    for (int j = 0; j < 4; ++j) {
        const int n = g * 4 + j;
        float m0w = Mw[0][n], m1w = Mw[1][n], m2w = Mw[2][n], m3w = Mw[3][n];
        float ms = fmaxf(fmaxf(m0w, m1w), fmaxf(m2w, m3w));
        float f0 = __expf(m0w - ms), f1 = __expf(m1w - ms);
        float f2 = __expf(m2w - ms), f3 = __expf(m3w - ms);
        float s = f0 * Osw[0][n][d] + f1 * Osw[1][n][d]
                + f2 * Osw[2][n][d] + f3 * Osw[3][n][d];
        float L = f0 * Lw[0][n] + f1 * Lw[1][n] + f2 * Lw[2][n] + f3 * Lw[3][n];
        vals[j] = s / L;
    }
    *(float4*)(msg + ((size_t)b * Dd + d * Hh + h) * Nn + n0 + g * 4) =
        make_float4(vals[0], vals[1], vals[2], vals[3]);
}

// ---------------------------------------------------------------------------
extern "C" void kernel_launch(void* const* d_in, const int* in_sizes, int n_in,
                              void* d_out, int out_size, void* d_ws, size_t ws_size,
                              hipStream_t stream) {
    const float* x      = (const float*)d_in[0];
    const float* source = (const float*)d_in[1];
    const float* mask   = (const float*)d_in[2];
    const float* Wq = (const float*)d_in[3];
    const float* bq = (const float*)d_in[4];
    const float* Wk = (const float*)d_in[5];
    const float* bk = (const float*)d_in[6];
    const float* Wv = (const float*)d_in[7];
    const float* bv = (const float*)d_in[8];
    const float* Wm = (const float*)d_in[9];
    const float* bm = (const float*)d_in[10];
    const float* W1 = (const float*)d_in[11];
    const float* b1 = (const float*)d_in[12];
    const float* gamma = (const float*)d_in[13];
    const float* beta  = (const float*)d_in[14];
    const float* rmean = (const float*)d_in[15];
    const float* rvar  = (const float*)d_in[16];
    const float* W2 = (const float*)d_in[17];
    const float* b2 = (const float*)d_in[18];
    float* outp = (float*)d_out;

    float* ws = (float*)d_ws;
    const size_t SZ = (size_t)Bb * Dd * Nn;  // 2,097,152 floats
    float* qb      = ws;
    float* kb      = ws + SZ;
    float* vb      = ws + 2 * SZ;
    float* msgb    = ws + 3 * SZ;
    float* msgproj = ws;             // reuses qb after attention
    float* hb      = ws + SZ;        // reuses kb+vb after prepack
    float* W1f     = ws + 4 * SZ;
    float* b1f     = W1f + D2 * D2;
    _Float16* Qt = (_Float16*)(ws + 4 * SZ + D2 * D2 + D2);
    _Float16* Kt = Qt + (size_t)Bb * Hh * Nn * 64;
    _Float16* Vt = Kt + (size_t)Bb * Hh * Mm * 64;

    fold_bn_kernel<<<D2, 256, 0, stream>>>(W1, b1, gamma, beta, rmean, rvar, W1f, b1f);

    dim3 gProj(Nn / 64, Dd / 64, Bb);
    gemm_kernel<<<gProj, 256, 0, stream>>>(Wq, bq, x,      nullptr, qb, Dd, Dd, Dd, 0);
    gemm_kernel<<<gProj, 256, 0, stream>>>(Wk, bk, source, nullptr, kb, Dd, Dd, Dd, 0);
    gemm_kernel<<<gProj, 256, 0, stream>>>(Wv, bv, source, nullptr, vb, Dd, Dd, Dd, 0);

    dim3 gPack(Nn / 64, Hh, Bb * 3);
    prepack_kernel<<<gPack, 256, 0, stream>>>(qb, kb, vb, Qt, Kt, Vt);

    dim3 gAttn(Nn / 16, Hh, Bb);
    attn_mfma_kernel<<<gAttn, 256, 0, stream>>>(Qt, Kt, Vt, mask, msgb);

    gemm_kernel<<<gProj, 256, 0, stream>>>(Wm, bm, msgb, nullptr, msgproj, Dd, Dd, Dd, 0);

    dim3 gW1(Nn / 64, D2 / 64, Bb);
    gemm_kernel<<<gW1, 256, 0, stream>>>(W1f, b1f, x, msgproj, hb, D2, Dd, D2, 1);

    gemm_kernel<<<gProj, 256, 0, stream>>>(W2, b2, hb, nullptr, outp, D2, D2, Dd, 0);
}

// Round 8
// 333.141 us; speedup vs baseline: 1.7639x; 1.3211x over previous
//
#include <hip/hip_runtime.h>

// Problem constants
constexpr int Bb = 4;     // batch
constexpr int Dd = 256;   // channels
constexpr int Nn = 2048;  // query positions
constexpr int Mm = 2048;  // source positions
constexpr int Hh = 4;     // heads
constexpr int D2 = 512;   // 2*D
constexpr int NT = Bb * Nn;  // 8192 total positions

#define FMAXV 3.402823466e38f

typedef _Float16 half8 __attribute__((ext_vector_type(8)));
typedef _Float16 half4v __attribute__((ext_vector_type(4)));
typedef float f32x4 __attribute__((ext_vector_type(4)));

// ---------------------------------------------------------------------------
// Weight prepack: fp32 -> fp16, with row permutation o' = h*64+d for q/k/v,
// column permutation for Wm (to match attention's [n][h*64+d] msg layout),
// BN fold for W1. Grid: 1792 blocks x 256 thr.
//   r in [0,256):    Wq' row r (perm), bq'
//   r in [256,768):  Wkv' row r-256 (k then v, perm), bkv'
//   r in [768,1024): Wm' row r-768 (cols perm)
//   r in [1024,1536):W1' row (BN-folded), b1f
//   r in [1536,1792):W2' row
// ---------------------------------------------------------------------------
__global__ __launch_bounds__(256)
void prep_weights_kernel(const float* __restrict__ Wq, const float* __restrict__ bq,
                         const float* __restrict__ Wk, const float* __restrict__ bk,
                         const float* __restrict__ Wv, const float* __restrict__ bv,
                         const float* __restrict__ Wm,
                         const float* __restrict__ W1, const float* __restrict__ b1,
                         const float* __restrict__ gamma, const float* __restrict__ beta,
                         const float* __restrict__ rmean, const float* __restrict__ rvar,
                         const float* __restrict__ W2,
                         _Float16* __restrict__ Wqp, float* __restrict__ bqp,
                         _Float16* __restrict__ Wkvp, float* __restrict__ bkvp,
                         _Float16* __restrict__ Wmp,
                         _Float16* __restrict__ W1p, float* __restrict__ b1f,
                         _Float16* __restrict__ W2p) {
    const int r = blockIdx.x, t = threadIdx.x;
    if (r < 256) {
        const int h = r >> 6, d = r & 63, so = d * Hh + h;
        Wqp[r * 256 + t] = (_Float16)Wq[so * 256 + t];
        if (t == 0) bqp[r] = bq[so];
    } else if (r < 768) {
        const int rr = r - 256, part = rr >> 8, o = rr & 255;
        const int h = o >> 6, d = o & 63, so = d * Hh + h;
        const float* Ws = part ? Wv : Wk;
        const float* bs = part ? bv : bk;
        Wkvp[rr * 256 + t] = (_Float16)Ws[so * 256 + t];
        if (t == 0) bkvp[rr] = bs[so];
    } else if (r < 1024) {
        const int o = r - 768;
        const int h = t >> 6, d = t & 63, sk = d * Hh + h;
        Wmp[o * 256 + t] = (_Float16)Wm[o * 256 + sk];
    } else if (r < 1536) {
        const int o = r - 1024;
        const float s = gamma[o] * rsqrtf(rvar[o] + 1e-3f);
        W1p[o * 512 + t]       = (_Float16)(W1[o * 512 + t] * s);
        W1p[o * 512 + t + 256] = (_Float16)(W1[o * 512 + t + 256] * s);
        if (t == 0) b1f[o] = (b1[o] - rmean[o]) * s + beta[o];
    } else {
        const int o = r - 1536;
        W2p[o * 512 + t]       = (_Float16)W2[o * 512 + t];
        W2p[o * 512 + t + 256] = (_Float16)W2[o * 512 + t + 256];
    }
}

// ---------------------------------------------------------------------------
// Activation prepack: x [b][256][2048] fp32 -> Yp[b][n][512] cols 0..256 fp16;
// source -> Sp[b][n][256] fp16. Transpose via LDS 64x64 tile.
// Grid (32, 4, 8): z = b*2 + which.
// ---------------------------------------------------------------------------
__global__ __launch_bounds__(256)
void prep_x_kernel(const float* __restrict__ x, const float* __restrict__ source,
                   _Float16* __restrict__ Yp, _Float16* __restrict__ Sp) {
    __shared__ _Float16 Ts[64][72];
    const int z = blockIdx.z, b = z >> 1, which = z & 1;
    const float* src = which ? source : x;
    _Float16* dst = which ? Sp : Yp;
    const int stride = which ? 256 : 512;
    const int c0 = blockIdx.y * 64, n0 = blockIdx.x * 64;
    const int t = threadIdx.x;
    const int cl = t >> 2, np = (t & 3) * 16;
    const float* sp = src + ((size_t)b * Dd + c0 + cl) * Nn + n0 + np;
    #pragma unroll
    for (int i = 0; i < 4; ++i) {
        float4 v = *(const float4*)(sp + i * 4);
        Ts[np + i * 4 + 0][cl] = (_Float16)v.x;
        Ts[np + i * 4 + 1][cl] = (_Float16)v.y;
        Ts[np + i * 4 + 2][cl] = (_Float16)v.z;
        Ts[np + i * 4 + 3][cl] = (_Float16)v.w;
    }
    __syncthreads();
    const int nl = t >> 2, cp = (t & 3) * 16;
    half8 a0 = *(const half8*)&Ts[nl][cp];
    half8 a1 = *(const half8*)&Ts[nl][cp + 8];
    _Float16* dp = dst + ((size_t)b * Nn + n0 + nl) * stride + c0 + cp;
    *(half8*)dp = a0;
    *(half8*)(dp + 8) = a1;
}

// ---------------------------------------------------------------------------
// fp16 MFMA GEMM: C[n][o] = bias[o] + sum_k A[n][k] * W[o][k].
// A: [NT][sA] fp16 (k-contiguous rows); W: [O][K] fp16. No LDS staging in the
// K-loop (direct global fragment loads), 2x2 waves of 64n x 64o per block.
// modeSel 0: fp16 out dst0 + n*sOut + o           (opt relu)
// modeSel 1: (kv) og<256 -> dst0 (mode0, s256); og>=256 -> dst1 V-layout
//            [(b*256 + (og-256))*2048 + m] fp16
// modeSel 2: fp32 out dstF [(b*256 + og)*2048 + m]
// ---------------------------------------------------------------------------
__global__ __launch_bounds__(256)
void gemm16_kernel(const _Float16* __restrict__ A, const _Float16* __restrict__ W,
                   const float* __restrict__ bias,
                   _Float16* __restrict__ dst0, _Float16* __restrict__ dst1,
                   float* __restrict__ dstF,
                   int K, int sA, int sOut, int modeSel, int relu) {
    __shared__ _Float16 Es[4][16][72];
    const int t = threadIdx.x;
    const int w = t >> 6, lane = t & 63, quad = lane >> 4, l16 = lane & 15;
    const int n0 = blockIdx.x * 128 + (w & 1) * 64;
    const int og0 = blockIdx.y * 128 + (w >> 1) * 64;

    f32x4 acc[4][4] = {};
    #pragma unroll 1
    for (int k0 = 0; k0 < K; k0 += 32) {
        half8 a[4], b[4];
        #pragma unroll
        for (int i = 0; i < 4; ++i)
            a[i] = *(const half8*)(A + (size_t)(n0 + i * 16 + l16) * sA + k0 + quad * 8);
        #pragma unroll
        for (int j = 0; j < 4; ++j)
            b[j] = *(const half8*)(W + (size_t)(og0 + j * 16 + l16) * K + k0 + quad * 8);
        #pragma unroll
        for (int i = 0; i < 4; ++i)
            #pragma unroll
            for (int j = 0; j < 4; ++j)
                acc[i][j] = __builtin_amdgcn_mfma_f32_16x16x32_f16(a[i], b[j], acc[i][j], 0, 0, 0);
    }

    float bcol[4];
    #pragma unroll
    for (int j = 0; j < 4; ++j) bcol[j] = bias[og0 + j * 16 + l16];

    int mode = 0, oloc0 = og0;
    if (modeSel == 2) mode = 2;
    else if (modeSel == 1 && og0 >= 256) { mode = 1; oloc0 = og0 - 256; }

    if (mode == 0) {
        #pragma unroll
        for (int i = 0; i < 4; ++i) {
            #pragma unroll
            for (int j = 0; j < 4; ++j)
                #pragma unroll
                for (int reg = 0; reg < 4; ++reg) {
                    float v = acc[i][j][reg] + bcol[j];
                    if (relu) v = fmaxf(v, 0.f);
                    Es[w][quad * 4 + reg][j * 16 + l16] = (_Float16)v;
                }
            __asm__ volatile("s_waitcnt lgkmcnt(0)" ::: "memory");
            const int row = lane & 15, oseg = (lane >> 4) * 16;
            half8 e0 = *(const half8*)&Es[w][row][oseg];
            half8 e1 = *(const half8*)&Es[w][row][oseg + 8];
            _Float16* dp = dst0 + (size_t)(n0 + i * 16 + row) * sOut + oloc0 + oseg;
            *(half8*)dp = e0;
            *(half8*)(dp + 8) = e1;
            __asm__ volatile("s_waitcnt lgkmcnt(0)" ::: "memory");
        }
    } else if (mode == 1) {
        #pragma unroll
        for (int i = 0; i < 4; ++i) {
            const int ng = n0 + i * 16 + quad * 4;
            const int bidx = ng >> 11, m0 = ng & 2047;
            #pragma unroll
            for (int j = 0; j < 4; ++j) {
                const int o = oloc0 + j * 16 + l16;
                half4v pv;
                #pragma unroll
                for (int reg = 0; reg < 4; ++reg) pv[reg] = (_Float16)(acc[i][j][reg] + bcol[j]);
                *(half4v*)(dst1 + ((size_t)bidx * 256 + o) * (size_t)Mm + m0) = pv;
            }
        }
    } else {
        #pragma unroll
        for (int i = 0; i < 4; ++i) {
            const int ng = n0 + i * 16 + quad * 4;
            const int bidx = ng >> 11, m0 = ng & 2047;
            #pragma unroll
            for (int j = 0; j < 4; ++j) {
                const int o = og0 + j * 16 + l16;
                f32x4 v;
                #pragma unroll
                for (int reg = 0; reg < 4; ++reg) v[reg] = acc[i][j][reg] + bcol[j];
                *(f32x4*)(dstF + ((size_t)bidx * 256 + o) * (size_t)Nn + m0) = v;
            }
        }
    }
}

// ---------------------------------------------------------------------------
// MFMA attention (R7-proven math: per-wave online max in 4-way m-split,
// max-aware combine). Changes vs R7: Q/K read from [b][n][256] fp16 head
// slices (row stride 256, offset h*64); msg written as fp16 [b][n][h*64+d].
// Grid (N/16, H, B) = 2048 blocks, 256 thr.
// ---------------------------------------------------------------------------
__global__ __launch_bounds__(256)
void attn_mfma_kernel(const _Float16* __restrict__ Qp, const _Float16* __restrict__ Kp,
                      const _Float16* __restrict__ Vt, const float* __restrict__ mask,
                      _Float16* __restrict__ msgp) {
    __shared__ __align__(16) _Float16 Ps[4][16][72];
    __shared__ __align__(16) float Osw[4][16][68];
    __shared__ float Lw[4][16];
    __shared__ float Mw[4][16];

    const int b = blockIdx.z, h = blockIdx.y, n0 = blockIdx.x * 16;
    const int t = threadIdx.x;
    const int w = t >> 6, lane = t & 63, quad = lane >> 4, l16 = lane & 15;

    const _Float16* qp = Qp + ((size_t)b * Nn + n0 + l16) * 256 + h * 64 + quad * 8;
    const half8 qa0 = *(const half8*)(qp);
    const half8 qa1 = *(const half8*)(qp + 32);

    const _Float16* Kbase = Kp + (size_t)b * Nn * 256 + h * 64;
    const _Float16* Vbase = Vt + ((size_t)b * 256 + h * 64 + l16) * (size_t)Mm;
    const float* mrow = mask + ((size_t)b * Nn + n0 + quad * 4) * Mm + l16;

    float mo[4] = {-FMAXV, -FMAXV, -FMAXV, -FMAXV};
    float lo[4] = {0.f, 0.f, 0.f, 0.f};
    f32x4 O[4] = {};

    const int mbeg = w * (Mm / 4);
    #pragma unroll 1
    for (int it = 0; it < (Mm / 4) / 64; ++it) {
        const int m0 = mbeg + it * 64;
        f32x4 S[4];
        #pragma unroll
        for (int mt = 0; mt < 4; ++mt) {
            const _Float16* kp = Kbase + (size_t)(m0 + mt * 16 + l16) * 256 + quad * 8;
            half8 k0 = *(const half8*)(kp);
            half8 k1 = *(const half8*)(kp + 32);
            f32x4 z = {0.f, 0.f, 0.f, 0.f};
            z = __builtin_amdgcn_mfma_f32_16x16x32_f16(qa0, k0, z, 0, 0, 0);
            z = __builtin_amdgcn_mfma_f32_16x16x32_f16(qa1, k1, z, 0, 0, 0);
            S[mt] = z;
        }
        float mk[4][4];
        #pragma unroll
        for (int mt = 0; mt < 4; ++mt)
            #pragma unroll
            for (int reg = 0; reg < 4; ++reg)
                mk[mt][reg] = mrow[(size_t)reg * Mm + m0 + mt * 16];
        #pragma unroll
        for (int mt = 0; mt < 4; ++mt)
            #pragma unroll
            for (int reg = 0; reg < 4; ++reg)
                S[mt][reg] = (mk[mt][reg] > 0.f) ? S[mt][reg] * 0.125f : -FMAXV;
        float mn[4], al[4];
        #pragma unroll
        for (int reg = 0; reg < 4; ++reg) {
            float mloc = fmaxf(fmaxf(S[0][reg], S[1][reg]), fmaxf(S[2][reg], S[3][reg]));
            #pragma unroll
            for (int off = 1; off < 16; off <<= 1)
                mloc = fmaxf(mloc, __shfl_xor(mloc, off));
            mn[reg] = fmaxf(mo[reg], mloc);
            al[reg] = __expf(mo[reg] - mn[reg]);
            mo[reg] = mn[reg];
        }
        float p[4][4];
        #pragma unroll
        for (int mt = 0; mt < 4; ++mt)
            #pragma unroll
            for (int reg = 0; reg < 4; ++reg)
                p[mt][reg] = __expf(S[mt][reg] - mn[reg]);
        #pragma unroll
        for (int reg = 0; reg < 4; ++reg)
            lo[reg] = lo[reg] * al[reg] + (p[0][reg] + p[1][reg]) + (p[2][reg] + p[3][reg]);
        #pragma unroll
        for (int mt = 0; mt < 4; ++mt)
            #pragma unroll
            for (int reg = 0; reg < 4; ++reg)
                Ps[w][quad * 4 + reg][mt * 16 + l16] = (_Float16)p[mt][reg];
        __asm__ volatile("s_waitcnt lgkmcnt(0)" ::: "memory");
        half8 pa0 = *(const half8*)&Ps[w][l16][quad * 8];
        half8 pa1 = *(const half8*)&Ps[w][l16][32 + quad * 8];
        #pragma unroll
        for (int dt = 0; dt < 4; ++dt)
            #pragma unroll
            for (int reg = 0; reg < 4; ++reg)
                O[dt][reg] *= al[reg];
        #pragma unroll
        for (int dt = 0; dt < 4; ++dt) {
            const _Float16* vp = Vbase + (size_t)(dt * 16) * Mm + m0 + quad * 8;
            half8 v0 = *(const half8*)(vp);
            half8 v1 = *(const half8*)(vp + 32);
            O[dt] = __builtin_amdgcn_mfma_f32_16x16x32_f16(pa0, v0, O[dt], 0, 0, 0);
            O[dt] = __builtin_amdgcn_mfma_f32_16x16x32_f16(pa1, v1, O[dt], 0, 0, 0);
        }
    }

    #pragma unroll
    for (int reg = 0; reg < 4; ++reg) {
        #pragma unroll
        for (int off = 1; off < 16; off <<= 1)
            lo[reg] += __shfl_xor(lo[reg], off);
    }

    #pragma unroll
    for (int dt = 0; dt < 4; ++dt)
        #pragma unroll
        for (int reg = 0; reg < 4; ++reg)
            Osw[w][quad * 4 + reg][dt * 16 + l16] = O[dt][reg];
    if (l16 == 0) {
        #pragma unroll
        for (int reg = 0; reg < 4; ++reg) {
            Lw[w][quad * 4 + reg] = lo[reg];
            Mw[w][quad * 4 + reg] = mo[reg];
        }
    }
    __syncthreads();

    // max-aware combine; write msgp[b][n][h*64+d] fp16
    const int nrow = t >> 4, dseg = (t & 15) * 4;
    const float m0w = Mw[0][nrow], m1w = Mw[1][nrow], m2w = Mw[2][nrow], m3w = Mw[3][nrow];
    const float ms = fmaxf(fmaxf(m0w, m1w), fmaxf(m2w, m3w));
    const float f0 = __expf(m0w - ms), f1 = __expf(m1w - ms);
    const float f2 = __expf(m2w - ms), f3 = __expf(m3w - ms);
    const float L = f0 * Lw[0][nrow] + f1 * Lw[1][nrow] + f2 * Lw[2][nrow] + f3 * Lw[3][nrow];
    const float inv = 1.0f / L;
    half4v outv;
    #pragma unroll
    for (int dd = 0; dd < 4; ++dd) {
        const int d = dseg + dd;
        float s = f0 * Osw[0][nrow][d] + f1 * Osw[1][nrow][d]
                + f2 * Osw[2][nrow][d] + f3 * Osw[3][nrow][d];
        outv[dd] = (_Float16)(s * inv);
    }
    *(half4v*)(msgp + ((size_t)b * Nn + n0 + nrow) * 256 + h * 64 + dseg) = outv;
}

// ---------------------------------------------------------------------------
extern "C" void kernel_launch(void* const* d_in, const int* in_sizes, int n_in,
                              void* d_out, int out_size, void* d_ws, size_t ws_size,
                              hipStream_t stream) {
    const float* x      = (const float*)d_in[0];
    const float* source = (const float*)d_in[1];
    const float* mask   = (const float*)d_in[2];
    const float* Wq = (const float*)d_in[3];
    const float* bq = (const float*)d_in[4];
    const float* Wk = (const float*)d_in[5];
    const float* bk = (const float*)d_in[6];
    const float* Wv = (const float*)d_in[7];
    const float* bv = (const float*)d_in[8];
    const float* Wm = (const float*)d_in[9];
    const float* bm = (const float*)d_in[10];
    const float* W1 = (const float*)d_in[11];
    const float* b1 = (const float*)d_in[12];
    const float* gamma = (const float*)d_in[13];
    const float* beta  = (const float*)d_in[14];
    const float* rmean = (const float*)d_in[15];
    const float* rvar  = (const float*)d_in[16];
    const float* W2 = (const float*)d_in[17];
    const float* b2 = (const float*)d_in[18];
    float* outp = (float*)d_out;

    // workspace layout (bytes)
    char* wsb = (char*)d_ws;
    _Float16* Yp   = (_Float16*)wsb;                       // [8192][512]  8 MB
    _Float16* Sp   = (_Float16*)(wsb + (8u << 20));        // [8192][256]  4 MB
    _Float16* Qp   = (_Float16*)(wsb + (12u << 20));       // [8192][256]  4 MB
    _Float16* Kp   = (_Float16*)(wsb + (16u << 20));       // [8192][256]  4 MB
    _Float16* Vt   = (_Float16*)(wsb + (20u << 20));       // [1024][2048] 4 MB
    _Float16* msgp = (_Float16*)(wsb + (24u << 20));       // [8192][256]  4 MB
    _Float16* Hp   = (_Float16*)(wsb + (28u << 20));       // [8192][512]  8 MB
    char* wp = wsb + (36u << 20);
    _Float16* Wqp  = (_Float16*)wp;            wp += 256 * 256 * 2;
    _Float16* Wkvp = (_Float16*)wp;            wp += 512 * 256 * 2;
    _Float16* Wmp  = (_Float16*)wp;            wp += 256 * 256 * 2;
    _Float16* W1p  = (_Float16*)wp;            wp += 512 * 512 * 2;
    _Float16* W2p  = (_Float16*)wp;            wp += 256 * 512 * 2;
    float* bqp  = (float*)wp;                  wp += 256 * 4;
    float* bkvp = (float*)wp;                  wp += 512 * 4;
    float* b1f  = (float*)wp;                  wp += 512 * 4;

    prep_weights_kernel<<<1792, 256, 0, stream>>>(
        Wq, bq, Wk, bk, Wv, bv, Wm, W1, b1, gamma, beta, rmean, rvar, W2,
        Wqp, bqp, Wkvp, bkvp, Wmp, W1p, b1f, W2p);

    dim3 gPrep(Nn / 64, Dd / 64, Bb * 2);
    prep_x_kernel<<<gPrep, 256, 0, stream>>>(x, source, Yp, Sp);

    // q projection: A=Yp (x cols 0..256, stride 512), out Qp [n][256]
    gemm16_kernel<<<dim3(NT / 128, 2), 256, 0, stream>>>(
        Yp, Wqp, bqp, Qp, nullptr, nullptr, 256, 512, 256, 0, 0);
    // k+v projections: A=Sp, out Kp (mode0) / Vt (mode1)
    gemm16_kernel<<<dim3(NT / 128, 4), 256, 0, stream>>>(
        Sp, Wkvp, bkvp, Kp, Vt, nullptr, 256, 256, 256, 1, 0);

    dim3 gAttn(Nn / 16, Hh, Bb);
    attn_mfma_kernel<<<gAttn, 256, 0, stream>>>(Qp, Kp, Vt, mask, msgp);

    // message projection: A=msgp, out -> Yp cols 256..512
    gemm16_kernel<<<dim3(NT / 128, 2), 256, 0, stream>>>(
        msgp, Wmp, bm, Yp + 256, nullptr, nullptr, 256, 256, 512, 0, 0);
    // MLP layer 1 (BN-folded, relu): A=Yp [n][512], out Hp [n][512]
    gemm16_kernel<<<dim3(NT / 128, 4), 256, 0, stream>>>(
        Yp, W1p, b1f, Hp, nullptr, nullptr, 512, 512, 512, 0, 1);
    // MLP layer 2: A=Hp, fp32 out [b][256][n]
    gemm16_kernel<<<dim3(NT / 128, 2), 256, 0, stream>>>(
        Hp, W2p, b2, nullptr, nullptr, outp, 512, 512, 0, 2, 0);
}